// Round 4
// baseline (229.379 us; speedup 1.0000x reference)
//
#include <hip/hip_runtime.h>
#include <math.h>

#define B_ 16
#define T_ 2048
#define D_ 256
#define W_ 128
#define M_ (B_*T_)   // 32768

typedef __attribute__((ext_vector_type(8))) short bf16x8;
typedef __attribute__((ext_vector_type(4))) float f32x4;
typedef unsigned short u16;

static __device__ __forceinline__ u16 f32_bf16_rne(float f) {
    unsigned int u = __float_as_uint(f);
    u += 0x7FFF + ((u >> 16) & 1);
    return (u16)(u >> 16);
}
static __device__ __forceinline__ float bf16_f32(u16 h) {
    return __uint_as_float(((unsigned int)h) << 16);
}
// async global->LDS, 16B per lane.  LDS dest = wave-uniform base + lane*16.
static __device__ __forceinline__ void gload_lds16(const u16* g, u16* l) {
    __builtin_amdgcn_global_load_lds(
        (const __attribute__((address_space(1))) void*)g,
        (__attribute__((address_space(3))) void*)l, 16, 0, 0);
}

// ---------------------------------------------------------------------------
// K0: transpose weights to bf16 [mat][n][k] via LDS tile (coalesced both
// sides).  hi for all 4 mats; lo for Wk only.  Grid (4 mats, 16 tiles 64x64).
// ---------------------------------------------------------------------------
__global__ __launch_bounds__(256) void aft_split_wT(
    const float* __restrict__ Wq, const float* __restrict__ Wk,
    const float* __restrict__ Wv, const float* __restrict__ Wo,
    u16* __restrict__ Wth, u16* __restrict__ Wkl)
{
    __shared__ alignas(16) u16 Th[64][72];
    __shared__ alignas(16) u16 Tl[64][72];
    const float* Ws[4] = {Wq, Wk, Wv, Wo};
    const int mat = blockIdx.x;
    const float* W = Ws[mat];
    const int k0 = (blockIdx.y & 3) * 64;
    const int n0 = (blockIdx.y >> 2) * 64;
    const int tid = threadIdx.x;

    #pragma unroll
    for (int p = 0; p < 4; ++p) {
        const int k = p * 16 + (tid >> 4);
        const int n = (tid & 15) * 4;
        float4 v = *(const float4*)&W[(size_t)(k0 + k) * 256 + n0 + n];
        float vv[4] = {v.x, v.y, v.z, v.w};
        #pragma unroll
        for (int e = 0; e < 4; ++e) {
            u16 h = f32_bf16_rne(vv[e]);
            Th[n + e][k] = h;
            Tl[n + e][k] = f32_bf16_rne(vv[e] - bf16_f32(h));
        }
    }
    __syncthreads();

    const int n  = tid >> 2;
    const int kc = (tid & 3) * 16;
    size_t ob = ((size_t)mat * 256 + n0 + n) * 256 + k0 + kc;
    *(uint4*)&Wth[ob]     = *(const uint4*)&Th[n][kc];
    *(uint4*)&Wth[ob + 8] = *(const uint4*)&Th[n][kc + 8];
    if (mat == 1) {
        size_t ol = ((size_t)(n0 + n)) * 256 + k0 + kc;
        *(uint4*)&Wkl[ol]     = *(const uint4*)&Tl[n][kc];
        *(uint4*)&Wkl[ol + 8] = *(const uint4*)&Tl[n][kc + 8];
    }
}

// ---------------------------------------------------------------------------
// K0b: banded EW precompute. EWb[t][j], j in [0,320): exp(wb[t][s])-1 inside
// band else 0, s = (t & ~63) - 128 + j.  bf16.
// ---------------------------------------------------------------------------
__global__ void aft_ewb(const float* __restrict__ wb, u16* __restrict__ EWb)
{
    const int t = blockIdx.x;
    const int j = threadIdx.x;   // blockDim = 320
    const int s = (t & ~63) - 128 + j;
    const int dlt = s - t;
    float v = 0.f;
    if (s >= 0 && s < T_ && dlt > -W_ && dlt < W_)
        v = expf(wb[(size_t)t * T_ + s]) - 1.0f;
    EWb[(size_t)t * 320 + j] = f32_bf16_rne(v);
}

// ---------------------------------------------------------------------------
// K1: QKV projections.  R3 post-mortem: conflicts-fix and dbuf-occupancy-loss
// canceled (49.2 vs 49.7); kernel is TLP/latency-bound (MfmaUtil 17, VALU 28,
// HBM 22%, occ 17.5 -- nothing saturated).  This version maximizes resident
// waves instead: 512-thread blocks (8 waves), M=128 x N=128, single-buffered
// 48KB staging -> 16 waves/CU (2 blocks, VGPR-capped), grid (256,2) = exactly
// 2 blocks/CU, one round, no tail.  xsplit kernel deleted: x fp32 is loaded
// directly, hi/lo-converted in-register (2x redundancy, was 4x in baseline),
// and written to the SAME swizzled LDS layout the verified R3 read path uses.
// B staged via global_load_lds (linear dest + pre-swizzled source, rule #21).
// k = 3-term split: xh*Wkh + xh*Wkl + xl*Wkh (bit-identical numerics).
// ---------------------------------------------------------------------------
__global__ __launch_bounds__(512, 4) void aft_qkv_mfma(
    const float* __restrict__ x,
    const u16* __restrict__ Wth, const u16* __restrict__ Wkl,
    u16* __restrict__ ekT, u16* __restrict__ sigqT)
{
    // main loop: Ah[128][32] + Al[128][32] + Bs[4][128][32] = 24576 u16 (48KB)
    // epilogue:  Tr[128][136] = 34816 u16 (68KB) reuses the same space
    __shared__ alignas(16) u16 sm[34816];
    u16* Ah = sm;               // [128][32]
    u16* Al = sm + 4096;        // [128][32]
    u16* Bs = sm + 8192;        // [4][128][32]: Wqh, Wkh, Wkl, Wvh
    u16* Tr = sm;               // [128][136] epilogue reuse

    const int tid  = threadIdx.x;
    const int row0 = blockIdx.x * 128;
    const int col0 = blockIdx.y * 128;
    const int b    = row0 >> 11;
    const int t0g  = row0 & (T_ - 1);
    const int lane = tid & 63;
    const int wid  = tid >> 6;           // 0..7
    const int wm   = (wid & 3) * 32;     // 4 M-groups of 32
    const int wn   = (wid >> 2) * 64;    // 2 N-groups of 64
    const int qd   = lane >> 4;
    const int r    = lane & 15;

    f32x4 accq[2][4], acck[2][4], accv[2][4];
    #pragma unroll
    for (int i = 0; i < 2; ++i)
        #pragma unroll
        for (int j = 0; j < 4; ++j) {
            accq[i][j] = (f32x4){0.f, 0.f, 0.f, 0.f};
            acck[i][j] = accq[i][j];
            accv[i][j] = accq[i][j];
        }

    // staging coords: 512 threads cover 128 rows x 32 cols (4 chunks of 8 u16)
    const int crow  = tid >> 2;                 // 0..127
    const int cswz  = (crow >> 1) & 3;          // row-dependent chunk XOR
    const int gchk  = tid & 3;                  // this thread's global chunk
    const int ccols = (gchk ^ cswz) * 8;        // pre-swizzled SOURCE col (B)
    const int aslot = crow * 32 + (gchk ^ cswz) * 8;  // swizzled LDS slot (A)
    const int wbase = wid * 512;                // gload dest: wave chunk
    // fragment-read slot with the matching XOR (verified R3: conflicts ~0)
    const int sq8   = (qd ^ ((r >> 1) & 3)) * 8;

    for (int k0 = 0; k0 < D_; k0 += 32) {
        if (k0) __syncthreads();          // compute(k-1) reads done
        // stage B: 4 tensors x 128 rows, linear dest + swizzled source
        {
            size_t gb = (size_t)(col0 + crow) * 256 + k0 + ccols;
            gload_lds16(&Wth[gb],          &Bs[0 * 4096 + wbase]);
            gload_lds16(&Wth[65536 + gb],  &Bs[1 * 4096 + wbase]);
            gload_lds16(&Wkl[gb],          &Bs[2 * 4096 + wbase]);
            gload_lds16(&Wth[131072 + gb], &Bs[3 * 4096 + wbase]);
        }
        // stage A: x fp32 -> bf16 hi/lo in-register -> swizzled ds_write
        {
            size_t ga = (size_t)(row0 + crow) * 256 + k0 + gchk * 8;
            float4 v0 = *(const float4*)&x[ga];
            float4 v1 = *(const float4*)&x[ga + 4];
            float vv[8] = {v0.x, v0.y, v0.z, v0.w, v1.x, v1.y, v1.z, v1.w};
            union { uint4 q; u16 h[8]; } H, L;
            #pragma unroll
            for (int e = 0; e < 8; ++e) {
                u16 h = f32_bf16_rne(vv[e]);
                H.h[e] = h;
                L.h[e] = f32_bf16_rne(vv[e] - bf16_f32(h));
            }
            *(uint4*)&Ah[aslot] = H.q;
            *(uint4*)&Al[aslot] = L.q;
        }
        __syncthreads();                  // drains vmcnt (B) + lgkm (A writes)

        bf16x8 ah[2], al[2];
        #pragma unroll
        for (int mf = 0; mf < 2; ++mf) {
            int ar = (wm + mf * 16 + r) * 32 + sq8;
            ah[mf] = *(const bf16x8*)&Ah[ar];
            al[mf] = *(const bf16x8*)&Al[ar];
        }
        #pragma unroll
        for (int nf = 0; nf < 4; ++nf) {
            int br = (wn + nf * 16 + r) * 32 + sq8;
            bf16x8 bq  = *(const bf16x8*)&Bs[br];
            bf16x8 bkh = *(const bf16x8*)&Bs[4096 + br];
            bf16x8 bkl = *(const bf16x8*)&Bs[8192 + br];
            bf16x8 bv  = *(const bf16x8*)&Bs[12288 + br];
            #pragma unroll
            for (int mf = 0; mf < 2; ++mf) {
                accq[mf][nf] = __builtin_amdgcn_mfma_f32_16x16x32_bf16(ah[mf], bq,  accq[mf][nf], 0, 0, 0);
                acck[mf][nf] = __builtin_amdgcn_mfma_f32_16x16x32_bf16(ah[mf], bkh, acck[mf][nf], 0, 0, 0);
                acck[mf][nf] = __builtin_amdgcn_mfma_f32_16x16x32_bf16(ah[mf], bkl, acck[mf][nf], 0, 0, 0);
                acck[mf][nf] = __builtin_amdgcn_mfma_f32_16x16x32_bf16(al[mf], bkh, acck[mf][nf], 0, 0, 0);
                accv[mf][nf] = __builtin_amdgcn_mfma_f32_16x16x32_bf16(ah[mf], bv,  accv[mf][nf], 0, 0, 0);
            }
        }
    }

    // epilogue: 3 LDS-transpose rounds (ek, ekv, sigq) -> global bf16
    const int dl_r = tid >> 2;            // 0..127
    const int tseg = (tid & 3) * 32;      // 0..96
    #pragma unroll
    for (int round = 0; round < 3; ++round) {
        __syncthreads();
        #pragma unroll
        for (int mf = 0; mf < 2; ++mf) {
            #pragma unroll
            for (int nf = 0; nf < 4; ++nf) {
                ushort4 o;
                float vals[4];
                #pragma unroll
                for (int reg = 0; reg < 4; ++reg) {
                    if (round == 0)      vals[reg] = expf(acck[mf][nf][reg]);
                    else if (round == 1) vals[reg] = expf(acck[mf][nf][reg]) * accv[mf][nf][reg];
                    else                 vals[reg] = 1.f / (1.f + expf(-accq[mf][nf][reg]));
                }
                o.x = f32_bf16_rne(vals[0]); o.y = f32_bf16_rne(vals[1]);
                o.z = f32_bf16_rne(vals[2]); o.w = f32_bf16_rne(vals[3]);
                int dl = wn + nf * 16 + r;
                int tt = wm + mf * 16 + qd * 4;
                *(ushort4*)&Tr[dl * 136 + tt] = o;
            }
        }
        __syncthreads();
        u16* dst;
        if (round == 0)      dst = ekT   + ((size_t)(b * 512 + col0 + dl_r)) * 2048;
        else if (round == 1) dst = ekT   + ((size_t)(b * 512 + 256 + col0 + dl_r)) * 2048;
        else                 dst = sigqT + ((size_t)(b * 256 + col0 + dl_r)) * 2048;
        dst += t0g + tseg;
        const u16* srcp = &Tr[dl_r * 136 + tseg];
        #pragma unroll
        for (int i = 0; i < 4; ++i)
            *(uint4*)&dst[i * 8] = *(const uint4*)&srcp[i * 8];
    }
}

// ---------------------------------------------------------------------------
// K2: row sums of ekT -> Sk (n<256), Sv (n>=256).  One wave per row, plain
// stores (no atomics, no memset needed).
// ---------------------------------------------------------------------------
__global__ __launch_bounds__(256) void aft_sums(
    const u16* __restrict__ ekT, float* __restrict__ Sk, float* __restrict__ Sv)
{
    const int wid  = threadIdx.x >> 6;
    const int lane = threadIdx.x & 63;
    const int row  = blockIdx.x * 4 + wid;   // 0..8191
    const int b = row >> 9, n = row & 511;
    const u16* p = ekT + (size_t)row * 2048 + lane * 32;
    float s = 0.f;
    #pragma unroll
    for (int c = 0; c < 4; ++c) {
        union { uint4 v; u16 h[8]; } u;
        u.v = *(const uint4*)&p[c * 8];
        #pragma unroll
        for (int i = 0; i < 8; ++i) s += bf16_f32(u.h[i]);
    }
    #pragma unroll
    for (int off = 32; off >= 1; off >>= 1) s += __shfl_down(s, off, 64);
    if (lane == 0) {
        if (n < 256) Sk[b * 256 + n] = s;
        else         Sv[b * 256 + n - 256] = s;
    }
}

// ---------------------------------------------------------------------------
// K3: banded num/den via bf16 MFMA.  Block = 64 t x 128 d; wave 64t x 32d
// holds num+den.  Epilogue: y = sig(q)*(Sv+num)/(Sk+den) -> y[b][t][d] bf16.
// ---------------------------------------------------------------------------
__global__ __launch_bounds__(256) void aft_band_mfma(
    const u16* __restrict__ EWb, const u16* __restrict__ ekT,
    const u16* __restrict__ sigqT,
    const float* __restrict__ Sk, const float* __restrict__ Sv,
    u16* __restrict__ yTD)
{
    __shared__ alignas(16) u16 sm[12800];
    u16* Aw  = sm;          // [64][40]
    u16* Bkv = sm + 2560;   // [256][40] : rows 0..127 ek, 128..255 ekv

    const int tid  = threadIdx.x;
    const int t0   = blockIdx.x * 64;
    const int b    = blockIdx.y >> 1;
    const int dh   = (blockIdx.y & 1) * 128;
    const int lane = tid & 63;
    const int wid  = tid >> 6;
    const int wn   = wid * 32;
    const int qd   = lane >> 4;
    const int r    = lane & 15;

    f32x4 accn[4][2], accd[4][2];
    #pragma unroll
    for (int i = 0; i < 4; ++i)
        #pragma unroll
        for (int j = 0; j < 2; ++j) {
            accn[i][j] = (f32x4){0.f, 0.f, 0.f, 0.f};
            accd[i][j] = (f32x4){0.f, 0.f, 0.f, 0.f};
        }

    const int atl = tid >> 2;          // 0..63
    const int ak8 = (tid & 3) * 8;     // 0,8,16,24

    for (int c = 0; c < 10; ++c) {
        const int sc = t0 - 128 + c * 32;
        if (sc < 0 || sc >= T_) continue;   // uniform per block; EW there is 0
        __syncthreads();
        *(uint4*)&Aw[atl * 40 + ak8] =
            *(const uint4*)&EWb[(size_t)(t0 + atl) * 320 + c * 32 + ak8];
        #pragma unroll
        for (int rr = 0; rr < 4; ++rr) {
            int nl = rr * 64 + atl;                        // 0..255
            int n  = (nl < 128) ? (dh + nl) : (256 + dh + nl - 128);
            *(uint4*)&Bkv[nl * 40 + ak8] =
                *(const uint4*)&ekT[((size_t)(b * 512) + n) * 2048 + sc + ak8];
        }
        __syncthreads();

        bf16x8 af[4];
        #pragma unroll
        for (int mf = 0; mf < 4; ++mf)
            af[mf] = *(const bf16x8*)&Aw[(mf * 16 + r) * 40 + qd * 8];
        #pragma unroll
        for (int nf = 0; nf < 2; ++nf) {
            bf16x8 be = *(const bf16x8*)&Bkv[(wn + nf * 16 + r) * 40 + qd * 8];
            bf16x8 bv = *(const bf16x8*)&Bkv[(128 + wn + nf * 16 + r) * 40 + qd * 8];
            #pragma unroll
            for (int mf = 0; mf < 4; ++mf) {
                accd[mf][nf] = __builtin_amdgcn_mfma_f32_16x16x32_bf16(af[mf], be, accd[mf][nf], 0, 0, 0);
                accn[mf][nf] = __builtin_amdgcn_mfma_f32_16x16x32_bf16(af[mf], bv, accn[mf][nf], 0, 0, 0);
            }
        }
    }

    // epilogue: y into LDS [t_local][136] then coalesced store to y[b][t][d]
    __syncthreads();
    u16* Ly = sm;    // [64][136]
    #pragma unroll
    for (int nf = 0; nf < 2; ++nf) {
        const int dl = wn + nf * 16 + r;
        const int d  = dh + dl;
        const float skq = Sk[(b << 8) + d];
        const float svq = Sv[(b << 8) + d];
        #pragma unroll
        for (int mf = 0; mf < 4; ++mf) {
            const int tt = t0 + mf * 16 + qd * 4;
            size_t off = ((size_t)(b << 8) + d) * 2048 + tt;
            ushort4 sg = *(const ushort4*)&sigqT[off];
            float s4[4] = {bf16_f32(sg.x), bf16_f32(sg.y), bf16_f32(sg.z), bf16_f32(sg.w)};
            #pragma unroll
            for (int reg = 0; reg < 4; ++reg) {
                float y = s4[reg] * (svq + accn[mf][nf][reg]) / (skq + accd[mf][nf][reg]);
                Ly[(mf * 16 + qd * 4 + reg) * 136 + dl] = f32_bf16_rne(y);
            }
        }
    }
    __syncthreads();
    {
        const int tl  = tid >> 2;          // 0..63
        const int ds4 = (tid & 3) * 32;    // 0..96
        u16* dst = yTD + ((size_t)b * 2048 + t0 + tl) * 256 + dh + ds4;
        #pragma unroll
        for (int i = 0; i < 4; ++i)
            *(uint4*)&dst[i * 8] = *(const uint4*)&Ly[tl * 136 + ds4 + i * 8];
    }
}

// ---------------------------------------------------------------------------
// K4: out = y @ Wo, single-bf16 both sides.  64 rows x 128 cols per block,
// grid (512, 2).  A staged from y[b][t][d] with vector loads/writes.
// ---------------------------------------------------------------------------
__global__ __launch_bounds__(256) void aft_out_mfma(
    const u16* __restrict__ yTD, const u16* __restrict__ Woth,
    float* __restrict__ out)
{
    __shared__ alignas(16) u16 sm[7680];
    u16* As = sm;           // [64][40]
    u16* Bh = sm + 2560;    // [128][40]

    const int tid  = threadIdx.x;
    const int row0 = blockIdx.x * 64;
    const int col0 = blockIdx.y * 128;
    const int lane = tid & 63;
    const int wid  = tid >> 6;
    const int wn   = wid * 32;
    const int qd   = lane >> 4;
    const int r    = lane & 15;

    f32x4 acc[4][2];
    #pragma unroll
    for (int i = 0; i < 4; ++i)
        #pragma unroll
        for (int j = 0; j < 2; ++j)
            acc[i][j] = (f32x4){0.f, 0.f, 0.f, 0.f};

    const int arow = tid >> 2;          // 0..63
    const int aseg = (tid & 3) * 8;
    const int brw  = tid >> 1;          // 0..127
    const int bsg  = (tid & 1) * 16;

    for (int k0 = 0; k0 < D_; k0 += 32) {
        {
            uint4 v = *(const uint4*)&yTD[(size_t)(row0 + arow) * 256 + k0 + aseg];
            *(uint4*)&As[arow * 40 + aseg] = v;
        }
        {
            size_t g = (size_t)(col0 + brw) * 256 + k0 + bsg;
            uint4 v0 = *(const uint4*)&Woth[g];
            uint4 v1 = *(const uint4*)&Woth[g + 8];
            *(uint4*)&Bh[brw * 40 + bsg]     = v0;
            *(uint4*)&Bh[brw * 40 + bsg + 8] = v1;
        }
        __syncthreads();

        bf16x8 af[4];
        #pragma unroll
        for (int mf = 0; mf < 4; ++mf)
            af[mf] = *(const bf16x8*)&As[(mf * 16 + r) * 40 + qd * 8];
        #pragma unroll
        for (int nf = 0; nf < 2; ++nf) {
            bf16x8 bh = *(const bf16x8*)&Bh[(wn + nf * 16 + r) * 40 + qd * 8];
            #pragma unroll
            for (int mf = 0; mf < 4; ++mf)
                acc[mf][nf] = __builtin_amdgcn_mfma_f32_16x16x32_bf16(af[mf], bh, acc[mf][nf], 0, 0, 0);
        }
        __syncthreads();
    }

    #pragma unroll
    for (int mf = 0; mf < 4; ++mf)
        #pragma unroll
        for (int nf = 0; nf < 2; ++nf)
            #pragma unroll
            for (int reg = 0; reg < 4; ++reg) {
                int mrow = row0 + mf * 16 + qd * 4 + reg;
                int ncol = col0 + wn + nf * 16 + r;
                out[(size_t)mrow * D_ + ncol] = acc[mf][nf][reg];
            }
}

extern "C" void kernel_launch(void* const* d_in, const int* in_sizes, int n_in,
                              void* d_out, int out_size, void* d_ws, size_t ws_size,
                              hipStream_t stream)
{
    const float* x  = (const float*)d_in[0];
    const float* Wq = (const float*)d_in[1];
    const float* Wk = (const float*)d_in[2];
    const float* Wv = (const float*)d_in[3];
    const float* Wo = (const float*)d_in[4];
    const float* wb = (const float*)d_in[5];
    // window (d_in[6]) is the constant 128, baked in as W_.

    u16* Wth   = (u16*)d_ws;                 // 4*65536 = 262144
    u16* Wkl   = Wth + 262144;               // 65536
    u16* EWb   = Wkl + 65536;                // 655360
    u16* ekT   = EWb + 655360;               // 16777216
    u16* sigqT = ekT + 16777216;             // 8388608
    u16* yTD   = sigqT + 8388608;            // 8388608
    float* Sk  = (float*)(yTD + 8388608);    // 4096
    float* Sv  = Sk + 4096;                  // 4096

    aft_split_wT<<<dim3(4, 16), 256, 0, stream>>>(Wq, Wk, Wv, Wo, Wth, Wkl);
    aft_ewb<<<dim3(T_), 320, 0, stream>>>(wb, EWb);
    aft_qkv_mfma<<<dim3(M_ / 128, 2), 512, 0, stream>>>(x, Wth, Wkl, ekT, sigqT);
    aft_sums<<<dim3(8192 / 4), 256, 0, stream>>>(ekT, Sk, Sv);
    aft_band_mfma<<<dim3(T_ / 64, B_ * 2), 256, 0, stream>>>(EWb, ekT, sigqT, Sk, Sv, yTD);
    aft_out_mfma<<<dim3(M_ / 64, 2), 256, 0, stream>>>(yTD, Wth + 3 * 65536, (float*)d_out);
}

// Round 5
// 194.271 us; speedup vs baseline: 1.1807x; 1.1807x over previous
//
#include <hip/hip_runtime.h>
#include <math.h>

#define B_ 16
#define T_ 2048
#define D_ 256
#define W_ 128
#define M_ (B_*T_)   // 32768

typedef __attribute__((ext_vector_type(8))) short bf16x8;
typedef __attribute__((ext_vector_type(4))) float f32x4;
typedef unsigned short u16;

static __device__ __forceinline__ u16 f32_bf16_rne(float f) {
    unsigned int u = __float_as_uint(f);
    u += 0x7FFF + ((u >> 16) & 1);
    return (u16)(u >> 16);
}
static __device__ __forceinline__ float bf16_f32(u16 h) {
    return __uint_as_float(((unsigned int)h) << 16);
}
// async global->LDS, 16B per lane.  LDS dest = wave-uniform base + lane*16.
static __device__ __forceinline__ void gload_lds16(const u16* g, u16* l) {
    __builtin_amdgcn_global_load_lds(
        (const __attribute__((address_space(1))) void*)g,
        (__attribute__((address_space(3))) void*)l, 16, 0, 0);
}

// ---------------------------------------------------------------------------
// K0: transpose weights to bf16 [mat][n][k] via LDS tile (coalesced both
// sides).  hi for all 4 mats; lo for Wk only.  Grid (4 mats, 16 tiles 64x64).
// ---------------------------------------------------------------------------
__global__ __launch_bounds__(256) void aft_split_wT(
    const float* __restrict__ Wq, const float* __restrict__ Wk,
    const float* __restrict__ Wv, const float* __restrict__ Wo,
    u16* __restrict__ Wth, u16* __restrict__ Wkl)
{
    __shared__ alignas(16) u16 Th[64][72];
    __shared__ alignas(16) u16 Tl[64][72];
    const float* Ws[4] = {Wq, Wk, Wv, Wo};
    const int mat = blockIdx.x;
    const float* W = Ws[mat];
    const int k0 = (blockIdx.y & 3) * 64;
    const int n0 = (blockIdx.y >> 2) * 64;
    const int tid = threadIdx.x;

    #pragma unroll
    for (int p = 0; p < 4; ++p) {
        const int k = p * 16 + (tid >> 4);
        const int n = (tid & 15) * 4;
        float4 v = *(const float4*)&W[(size_t)(k0 + k) * 256 + n0 + n];
        float vv[4] = {v.x, v.y, v.z, v.w};
        #pragma unroll
        for (int e = 0; e < 4; ++e) {
            u16 h = f32_bf16_rne(vv[e]);
            Th[n + e][k] = h;
            Tl[n + e][k] = f32_bf16_rne(vv[e] - bf16_f32(h));
        }
    }
    __syncthreads();

    const int n  = tid >> 2;
    const int kc = (tid & 3) * 16;
    size_t ob = ((size_t)mat * 256 + n0 + n) * 256 + k0 + kc;
    *(uint4*)&Wth[ob]     = *(const uint4*)&Th[n][kc];
    *(uint4*)&Wth[ob + 8] = *(const uint4*)&Th[n][kc + 8];
    if (mat == 1) {
        size_t ol = ((size_t)(n0 + n)) * 256 + k0 + kc;
        *(uint4*)&Wkl[ol]     = *(const uint4*)&Tl[n][kc];
        *(uint4*)&Wkl[ol + 8] = *(const uint4*)&Tl[n][kc + 8];
    }
}

// ---------------------------------------------------------------------------
// K0b: banded EW precompute. EWb[t][j], j in [0,320): exp(wb[t][s])-1 inside
// band else 0, s = (t & ~63) - 128 + j.  bf16.
// ---------------------------------------------------------------------------
__global__ void aft_ewb(const float* __restrict__ wb, u16* __restrict__ EWb)
{
    const int t = blockIdx.x;
    const int j = threadIdx.x;   // blockDim = 320
    const int s = (t & ~63) - 128 + j;
    const int dlt = s - t;
    float v = 0.f;
    if (s >= 0 && s < T_ && dlt > -W_ && dlt < W_)
        v = expf(wb[(size_t)t * T_ + s]) - 1.0f;
    EWb[(size_t)t * 320 + j] = f32_bf16_rne(v);
}

// ---------------------------------------------------------------------------
// K1: QKV projections.  R4 post-mortem: launch_bounds(512,4) forced a 128-reg
// cap against a ~210-reg kernel -> scratch spills (WRITE_SIZE 50->176MB), 81us.
// Root constraint: 96 acc regs (3 tensors x 64x32 wave tile) cap residency at
// 2 waves/SIMD.  Fix: wave tile 32x32 -> acc 48 regs, total ~120-140, and
// __launch_bounds__(256,3) (cap ~170, safe margin) -> 12 waves/CU (1.5x R2).
// Block 64x64, 4 waves (2Mx2N), single-buffered 24KB LDS, 2-barrier loop.
// B staged via global_load_lds (linear dest + pre-swizzled source, rule #21);
// A (x fp32) converted in-register and ds_written to the same swizzled layout
// (xsplit kernel deleted).  Fragment reads use the R3-verified XOR swizzle
// (conflict-free).  k = 3-term split: xh*Wkh + xh*Wkl + xl*Wkh (bit-identical).
// ---------------------------------------------------------------------------
__global__ __launch_bounds__(256, 3) void aft_qkv_mfma(
    const float* __restrict__ x,
    const u16* __restrict__ Wth, const u16* __restrict__ Wkl,
    u16* __restrict__ ekT, u16* __restrict__ sigqT)
{
    // main loop: Ah[64][32] + Al[64][32] + Bs[4][64][32] = 12288 u16 (24KB)
    // epilogue:  Tr[64][72] = 4608 u16 reuses the same space
    __shared__ alignas(16) u16 sm[12288];
    u16* Ah = sm;               // [64][32]
    u16* Al = sm + 2048;        // [64][32]
    u16* Bs = sm + 4096;        // [4][64][32]: Wqh, Wkh, Wkl, Wvh
    u16* Tr = sm;               // [64][72] epilogue reuse

    const int tid  = threadIdx.x;
    const int row0 = blockIdx.x * 64;
    const int col0 = blockIdx.y * 64;
    const int b    = row0 >> 11;
    const int t0g  = row0 & (T_ - 1);
    const int lane = tid & 63;
    const int wid  = tid >> 6;           // 0..3
    const int wm   = (wid >> 1) * 32;    // 2 M-groups of 32
    const int wn   = (wid & 1) * 32;     // 2 N-groups of 32
    const int qd   = lane >> 4;
    const int r    = lane & 15;

    f32x4 accq[2][2], acck[2][2], accv[2][2];
    #pragma unroll
    for (int i = 0; i < 2; ++i)
        #pragma unroll
        for (int j = 0; j < 2; ++j) {
            accq[i][j] = (f32x4){0.f, 0.f, 0.f, 0.f};
            acck[i][j] = accq[i][j];
            accv[i][j] = accq[i][j];
        }

    // staging coords: 256 threads cover 64 rows x 32 cols (4 chunks of 8 u16)
    const int crow  = tid >> 2;                 // 0..63
    const int gchk  = tid & 3;                  // this thread's global chunk
    const int cswz  = (crow >> 1) & 3;          // row-dependent chunk XOR
    const int ccols = (gchk ^ cswz) * 8;        // pre-swizzled SOURCE col (B)
    const int aslot = crow * 32 + (gchk ^ cswz) * 8;  // swizzled LDS slot (A)
    const int wbase = wid * 512;                // gload dest: wave chunk (u16)
    // fragment-read slot with the matching XOR (verified R3: conflicts ~0)
    const int sq8   = (qd ^ ((r >> 1) & 3)) * 8;

    for (int k0 = 0; k0 < D_; k0 += 32) {
        if (k0) __syncthreads();          // compute(k-1) reads done
        // stage B: 4 tensors x 64 rows, linear dest + swizzled source
        {
            size_t gb = (size_t)(col0 + crow) * 256 + k0 + ccols;
            gload_lds16(&Wth[gb],          &Bs[0 * 2048 + wbase]);
            gload_lds16(&Wth[65536 + gb],  &Bs[1 * 2048 + wbase]);
            gload_lds16(&Wkl[gb],          &Bs[2 * 2048 + wbase]);
            gload_lds16(&Wth[131072 + gb], &Bs[3 * 2048 + wbase]);
        }
        // stage A: x fp32 -> bf16 hi/lo in-register -> swizzled ds_write
        {
            size_t ga = (size_t)(row0 + crow) * 256 + k0 + gchk * 8;
            float4 v0 = *(const float4*)&x[ga];
            float4 v1 = *(const float4*)&x[ga + 4];
            float vv[8] = {v0.x, v0.y, v0.z, v0.w, v1.x, v1.y, v1.z, v1.w};
            union { uint4 q; u16 h[8]; } H, L;
            #pragma unroll
            for (int e = 0; e < 8; ++e) {
                u16 h = f32_bf16_rne(vv[e]);
                H.h[e] = h;
                L.h[e] = f32_bf16_rne(vv[e] - bf16_f32(h));
            }
            *(uint4*)&Ah[aslot] = H.q;
            *(uint4*)&Al[aslot] = L.q;
        }
        __syncthreads();                  // drains vmcnt (B) + lgkm (A writes)

        bf16x8 ah[2], al[2];
        #pragma unroll
        for (int mf = 0; mf < 2; ++mf) {
            int ar = (wm + mf * 16 + r) * 32 + sq8;
            ah[mf] = *(const bf16x8*)&Ah[ar];
            al[mf] = *(const bf16x8*)&Al[ar];
        }
        #pragma unroll
        for (int nf = 0; nf < 2; ++nf) {
            int br = (wn + nf * 16 + r) * 32 + sq8;
            bf16x8 bq  = *(const bf16x8*)&Bs[br];
            bf16x8 bkh = *(const bf16x8*)&Bs[2048 + br];
            bf16x8 bkl = *(const bf16x8*)&Bs[4096 + br];
            bf16x8 bv  = *(const bf16x8*)&Bs[6144 + br];
            #pragma unroll
            for (int mf = 0; mf < 2; ++mf) {
                accq[mf][nf] = __builtin_amdgcn_mfma_f32_16x16x32_bf16(ah[mf], bq,  accq[mf][nf], 0, 0, 0);
                acck[mf][nf] = __builtin_amdgcn_mfma_f32_16x16x32_bf16(ah[mf], bkh, acck[mf][nf], 0, 0, 0);
                acck[mf][nf] = __builtin_amdgcn_mfma_f32_16x16x32_bf16(ah[mf], bkl, acck[mf][nf], 0, 0, 0);
                acck[mf][nf] = __builtin_amdgcn_mfma_f32_16x16x32_bf16(al[mf], bkh, acck[mf][nf], 0, 0, 0);
                accv[mf][nf] = __builtin_amdgcn_mfma_f32_16x16x32_bf16(ah[mf], bv,  accv[mf][nf], 0, 0, 0);
            }
        }
    }

    // epilogue: 3 LDS-transpose rounds (ek, ekv, sigq) -> global bf16
    const int dl_r = tid >> 2;            // 0..63
    const int tseg = (tid & 3) * 16;      // 0..48
    #pragma unroll
    for (int round = 0; round < 3; ++round) {
        __syncthreads();
        #pragma unroll
        for (int mf = 0; mf < 2; ++mf) {
            #pragma unroll
            for (int nf = 0; nf < 2; ++nf) {
                ushort4 o;
                float vals[4];
                #pragma unroll
                for (int reg = 0; reg < 4; ++reg) {
                    if (round == 0)      vals[reg] = expf(acck[mf][nf][reg]);
                    else if (round == 1) vals[reg] = expf(acck[mf][nf][reg]) * accv[mf][nf][reg];
                    else                 vals[reg] = 1.f / (1.f + expf(-accq[mf][nf][reg]));
                }
                o.x = f32_bf16_rne(vals[0]); o.y = f32_bf16_rne(vals[1]);
                o.z = f32_bf16_rne(vals[2]); o.w = f32_bf16_rne(vals[3]);
                int dl = wn + nf * 16 + r;
                int tt = wm + mf * 16 + qd * 4;
                *(ushort4*)&Tr[dl * 72 + tt] = o;
            }
        }
        __syncthreads();
        u16* dst;
        if (round == 0)      dst = ekT   + ((size_t)(b * 512 + col0 + dl_r)) * 2048;
        else if (round == 1) dst = ekT   + ((size_t)(b * 512 + 256 + col0 + dl_r)) * 2048;
        else                 dst = sigqT + ((size_t)(b * 256 + col0 + dl_r)) * 2048;
        dst += t0g + tseg;
        const u16* srcp = &Tr[dl_r * 72 + tseg];
        *(uint4*)&dst[0] = *(const uint4*)&srcp[0];
        *(uint4*)&dst[8] = *(const uint4*)&srcp[8];
    }
}

// ---------------------------------------------------------------------------
// K2: row sums of ekT -> Sk (n<256), Sv (n>=256).  One wave per row, plain
// stores (no atomics, no memset needed).
// ---------------------------------------------------------------------------
__global__ __launch_bounds__(256) void aft_sums(
    const u16* __restrict__ ekT, float* __restrict__ Sk, float* __restrict__ Sv)
{
    const int wid  = threadIdx.x >> 6;
    const int lane = threadIdx.x & 63;
    const int row  = blockIdx.x * 4 + wid;   // 0..8191
    const int b = row >> 9, n = row & 511;
    const u16* p = ekT + (size_t)row * 2048 + lane * 32;
    float s = 0.f;
    #pragma unroll
    for (int c = 0; c < 4; ++c) {
        union { uint4 v; u16 h[8]; } u;
        u.v = *(const uint4*)&p[c * 8];
        #pragma unroll
        for (int i = 0; i < 8; ++i) s += bf16_f32(u.h[i]);
    }
    #pragma unroll
    for (int off = 32; off >= 1; off >>= 1) s += __shfl_down(s, off, 64);
    if (lane == 0) {
        if (n < 256) Sk[b * 256 + n] = s;
        else         Sv[b * 256 + n - 256] = s;
    }
}

// ---------------------------------------------------------------------------
// K3: banded num/den via bf16 MFMA.  Block = 64 t x 128 d; wave 64t x 32d
// holds num+den.  Epilogue: y = sig(q)*(Sv+num)/(Sk+den) -> y[b][t][d] bf16.
// ---------------------------------------------------------------------------
__global__ __launch_bounds__(256) void aft_band_mfma(
    const u16* __restrict__ EWb, const u16* __restrict__ ekT,
    const u16* __restrict__ sigqT,
    const float* __restrict__ Sk, const float* __restrict__ Sv,
    u16* __restrict__ yTD)
{
    __shared__ alignas(16) u16 sm[12800];
    u16* Aw  = sm;          // [64][40]
    u16* Bkv = sm + 2560;   // [256][40] : rows 0..127 ek, 128..255 ekv

    const int tid  = threadIdx.x;
    const int t0   = blockIdx.x * 64;
    const int b    = blockIdx.y >> 1;
    const int dh   = (blockIdx.y & 1) * 128;
    const int lane = tid & 63;
    const int wid  = tid >> 6;
    const int wn   = wid * 32;
    const int qd   = lane >> 4;
    const int r    = lane & 15;

    f32x4 accn[4][2], accd[4][2];
    #pragma unroll
    for (int i = 0; i < 4; ++i)
        #pragma unroll
        for (int j = 0; j < 2; ++j) {
            accn[i][j] = (f32x4){0.f, 0.f, 0.f, 0.f};
            accd[i][j] = (f32x4){0.f, 0.f, 0.f, 0.f};
        }

    const int atl = tid >> 2;          // 0..63
    const int ak8 = (tid & 3) * 8;     // 0,8,16,24

    for (int c = 0; c < 10; ++c) {
        const int sc = t0 - 128 + c * 32;
        if (sc < 0 || sc >= T_) continue;   // uniform per block; EW there is 0
        __syncthreads();
        *(uint4*)&Aw[atl * 40 + ak8] =
            *(const uint4*)&EWb[(size_t)(t0 + atl) * 320 + c * 32 + ak8];
        #pragma unroll
        for (int rr = 0; rr < 4; ++rr) {
            int nl = rr * 64 + atl;                        // 0..255
            int n  = (nl < 128) ? (dh + nl) : (256 + dh + nl - 128);
            *(uint4*)&Bkv[nl * 40 + ak8] =
                *(const uint4*)&ekT[((size_t)(b * 512) + n) * 2048 + sc + ak8];
        }
        __syncthreads();

        bf16x8 af[4];
        #pragma unroll
        for (int mf = 0; mf < 4; ++mf)
            af[mf] = *(const bf16x8*)&Aw[(mf * 16 + r) * 40 + qd * 8];
        #pragma unroll
        for (int nf = 0; nf < 2; ++nf) {
            bf16x8 be = *(const bf16x8*)&Bkv[(wn + nf * 16 + r) * 40 + qd * 8];
            bf16x8 bv = *(const bf16x8*)&Bkv[(128 + wn + nf * 16 + r) * 40 + qd * 8];
            #pragma unroll
            for (int mf = 0; mf < 4; ++mf) {
                accd[mf][nf] = __builtin_amdgcn_mfma_f32_16x16x32_bf16(af[mf], be, accd[mf][nf], 0, 0, 0);
                accn[mf][nf] = __builtin_amdgcn_mfma_f32_16x16x32_bf16(af[mf], bv, accn[mf][nf], 0, 0, 0);
            }
        }
    }

    // epilogue: y into LDS [t_local][136] then coalesced store to y[b][t][d]
    __syncthreads();
    u16* Ly = sm;    // [64][136]
    #pragma unroll
    for (int nf = 0; nf < 2; ++nf) {
        const int dl = wn + nf * 16 + r;
        const int d  = dh + dl;
        const float skq = Sk[(b << 8) + d];
        const float svq = Sv[(b << 8) + d];
        #pragma unroll
        for (int mf = 0; mf < 4; ++mf) {
            const int tt = t0 + mf * 16 + qd * 4;
            size_t off = ((size_t)(b << 8) + d) * 2048 + tt;
            ushort4 sg = *(const ushort4*)&sigqT[off];
            float s4[4] = {bf16_f32(sg.x), bf16_f32(sg.y), bf16_f32(sg.z), bf16_f32(sg.w)};
            #pragma unroll
            for (int reg = 0; reg < 4; ++reg) {
                float y = s4[reg] * (svq + accn[mf][nf][reg]) / (skq + accd[mf][nf][reg]);
                Ly[(mf * 16 + qd * 4 + reg) * 136 + dl] = f32_bf16_rne(y);
            }
        }
    }
    __syncthreads();
    {
        const int tl  = tid >> 2;          // 0..63
        const int ds4 = (tid & 3) * 32;    // 0..96
        u16* dst = yTD + ((size_t)b * 2048 + t0 + tl) * 256 + dh + ds4;
        #pragma unroll
        for (int i = 0; i < 4; ++i)
            *(uint4*)&dst[i * 8] = *(const uint4*)&Ly[tl * 136 + ds4 + i * 8];
    }
}

// ---------------------------------------------------------------------------
// K4: out = y @ Wo, single-bf16 both sides.  64 rows x 128 cols per block,
// grid (512, 2).  A staged from y[b][t][d] with vector loads/writes.
// ---------------------------------------------------------------------------
__global__ __launch_bounds__(256) void aft_out_mfma(
    const u16* __restrict__ yTD, const u16* __restrict__ Woth,
    float* __restrict__ out)
{
    __shared__ alignas(16) u16 sm[7680];
    u16* As = sm;           // [64][40]
    u16* Bh = sm + 2560;    // [128][40]

    const int tid  = threadIdx.x;
    const int row0 = blockIdx.x * 64;
    const int col0 = blockIdx.y * 128;
    const int lane = tid & 63;
    const int wid  = tid >> 6;
    const int wn   = wid * 32;
    const int qd   = lane >> 4;
    const int r    = lane & 15;

    f32x4 acc[4][2];
    #pragma unroll
    for (int i = 0; i < 4; ++i)
        #pragma unroll
        for (int j = 0; j < 2; ++j)
            acc[i][j] = (f32x4){0.f, 0.f, 0.f, 0.f};

    const int arow = tid >> 2;          // 0..63
    const int aseg = (tid & 3) * 8;
    const int brw  = tid >> 1;          // 0..127
    const int bsg  = (tid & 1) * 16;

    for (int k0 = 0; k0 < D_; k0 += 32) {
        {
            uint4 v = *(const uint4*)&yTD[(size_t)(row0 + arow) * 256 + k0 + aseg];
            *(uint4*)&As[arow * 40 + aseg] = v;
        }
        {
            size_t g = (size_t)(col0 + brw) * 256 + k0 + bsg;
            uint4 v0 = *(const uint4*)&Woth[g];
            uint4 v1 = *(const uint4*)&Woth[g + 8];
            *(uint4*)&Bh[brw * 40 + bsg]     = v0;
            *(uint4*)&Bh[brw * 40 + bsg + 8] = v1;
        }
        __syncthreads();

        bf16x8 af[4];
        #pragma unroll
        for (int mf = 0; mf < 4; ++mf)
            af[mf] = *(const bf16x8*)&As[(mf * 16 + r) * 40 + qd * 8];
        #pragma unroll
        for (int nf = 0; nf < 2; ++nf) {
            bf16x8 bh = *(const bf16x8*)&Bh[(wn + nf * 16 + r) * 40 + qd * 8];
            #pragma unroll
            for (int mf = 0; mf < 4; ++mf)
                acc[mf][nf] = __builtin_amdgcn_mfma_f32_16x16x32_bf16(af[mf], bh, acc[mf][nf], 0, 0, 0);
        }
        __syncthreads();
    }

    #pragma unroll
    for (int mf = 0; mf < 4; ++mf)
        #pragma unroll
        for (int nf = 0; nf < 2; ++nf)
            #pragma unroll
            for (int reg = 0; reg < 4; ++reg) {
                int mrow = row0 + mf * 16 + qd * 4 + reg;
                int ncol = col0 + wn + nf * 16 + r;
                out[(size_t)mrow * D_ + ncol] = acc[mf][nf][reg];
            }
}

extern "C" void kernel_launch(void* const* d_in, const int* in_sizes, int n_in,
                              void* d_out, int out_size, void* d_ws, size_t ws_size,
                              hipStream_t stream)
{
    const float* x  = (const float*)d_in[0];
    const float* Wq = (const float*)d_in[1];
    const float* Wk = (const float*)d_in[2];
    const float* Wv = (const float*)d_in[3];
    const float* Wo = (const float*)d_in[4];
    const float* wb = (const float*)d_in[5];
    // window (d_in[6]) is the constant 128, baked in as W_.

    u16* Wth   = (u16*)d_ws;                 // 4*65536 = 262144
    u16* Wkl   = Wth + 262144;               // 65536
    u16* EWb   = Wkl + 65536;                // 655360
    u16* ekT   = EWb + 655360;               // 16777216
    u16* sigqT = ekT + 16777216;             // 8388608
    u16* yTD   = sigqT + 8388608;            // 8388608
    float* Sk  = (float*)(yTD + 8388608);    // 4096
    float* Sv  = Sk + 4096;                  // 4096

    aft_split_wT<<<dim3(4, 16), 256, 0, stream>>>(Wq, Wk, Wv, Wo, Wth, Wkl);
    aft_ewb<<<dim3(T_), 320, 0, stream>>>(wb, EWb);
    aft_qkv_mfma<<<dim3(M_ / 64, 4), 256, 0, stream>>>(x, Wth, Wkl, ekT, sigqT);
    aft_sums<<<dim3(8192 / 4), 256, 0, stream>>>(ekT, Sk, Sv);
    aft_band_mfma<<<dim3(T_ / 64, B_ * 2), 256, 0, stream>>>(EWb, ekT, sigqT, Sk, Sv, yTD);
    aft_out_mfma<<<dim3(M_ / 64, 2), 256, 0, stream>>>(yTD, Wth + 3 * 65536, (float*)d_out);
}